// Round 7
// baseline (585.287 us; speedup 1.0000x reference)
//
#include <hip/hip_runtime.h>

// Problem constants (fixed by setup_inputs)
#define BB 4
#define Q 75
#define WAY 5
#define HW 100
#define D 640
#define M 500          // shot*HW
#define QROWS 7500     // Q*HW
#define NRF 472        // padded row-frags per b: 59 blocks * 8 (7552 rows)

// ws layout: floats at low offsets, pre-split frag-order arrays after.
// TOTAL ws ask: ~99.8 MB (unchanged).
#define WS_QINV 0
#define WS_SINV 30000
#define WS_QMEAN 40000     // BB*Q*D = 192000 (now: SUM over h of qn)
#define WS_PROTO 232000    // BB*WAY*D = 12800 (now: SUM over m of sn)
#define WS_FEAT 244800    // BB*Q*10 = 3000
#define WS_BH_BYTE 1048576u                       // 20*32*20*1024 = 13107200
#define WS_BL_BYTE (1048576u + 13107200u)         // 14155776
#define WS_AH_BYTE (14155776u + 13107200u)        // 27262976; 4*472*20*1024 = 38666240
#define WS_AL_BYTE (27262976u + 38666240u)        // 65929216; end 104595456

using short8  = __attribute__((ext_vector_type(8))) short;
using short4v = __attribute__((ext_vector_type(4))) short;
using float4v = __attribute__((ext_vector_type(4))) float;

__device__ __forceinline__ void split1(float v, unsigned short& h, unsigned short& l) {
    unsigned u = __float_as_uint(v);
    unsigned short hu = (unsigned short)(u >> 16);          // truncate to bf16
    float hf = __uint_as_float(u & 0xffff0000u);
    float lo = v - hf;                                       // exact residual
    unsigned short lu = (unsigned short)(__float_as_uint(lo) >> 16);
    h = hu; l = lu;
}

__device__ __forceinline__ void split_store(float4 v, float s, short* dh, short* dl) {
    unsigned short h0,h1,h2,h3,l0,l1,l2,l3;
    split1(v.x * s, h0, l0); split1(v.y * s, h1, l1);
    split1(v.z * s, h2, l2); split1(v.w * s, h3, l3);
    short4v hv, lv;
    hv[0]=(short)h0; hv[1]=(short)h1; hv[2]=(short)h2; hv[3]=(short)h3;
    lv[0]=(short)l0; lv[1]=(short)l1; lv[2]=(short)l2; lv[3]=(short)l3;
    *(short4v*)dh = hv;
    *(short4v*)dl = lv;
}

// ---------------- kernel init: zero the qmean/proto accumulators ---------------
__global__ void zero_kernel(float* __restrict__ ws) {
    int i = blockIdx.x * blockDim.x + threadIdx.x;
    // zero floats [WS_QMEAN, WS_FEAT) = 204800 floats
    for (int k = i; k < 204800; k += 256 * 256) ws[WS_QMEAN + k] = 0.f;
}

// ---------------- kernel 0: merged pre-split A+B (+ fused mean partial sums) ---
// bid < 640: B-mode (bw = bid>>5, rf = bid&31). Else A-mode over (b, rf).
// Normalizes rows, writes bf16 hi/lo frag-order arrays, and accumulates the
// per-(b,q) / per-(b,w) SUMS of normalized rows into WS_QMEAN / WS_PROTO via
// LDS partials + global atomicAdd (replaces the old means_kernel entirely).
__global__ __launch_bounds__(256) void presplit_ab(const float* __restrict__ xq,
                                                   const float* __restrict__ xs,
                                                   float* __restrict__ ws) {
    __shared__ float partial[256];
    __shared__ float invS[16];
    __shared__ short Sh[16][648];
    __shared__ short Sl[16][648];
    __shared__ float acc2[2][640];
    int bid = blockIdx.x;
    int tid = threadIdx.x;
    for (int i = tid; i < 1280; i += 256) ((float*)acc2)[i] = 0.f;
    int rho = tid & 15;
    int kc  = tid >> 4;            // 0..15, k in [kc*40, kc*40+40)

    bool isB = (bid < 640);
    int bw = 0, rf = 0, b = 0, r = 0;
    bool valid;
    const float* src;
    if (isB) {
        bw = bid >> 5; rf = bid & 31;
        r = rf * 16 + rho;
        valid = (r < M);
        src = xs + ((size_t)bw * M + (valid ? r : 0)) * D + kc * 40;
    } else {
        int a = bid - 640;
        b = a / NRF; rf = a % NRF;
        r = rf * 16 + rho;
        valid = (r < QROWS);
        src = xq + ((size_t)b * QROWS + (valid ? r : 0)) * D + kc * 40;
    }

    float4 v[10];
    float ss = 0.f;
    #pragma unroll
    for (int i = 0; i < 10; ++i) {
        v[i] = valid ? *(const float4*)(src + i * 4) : make_float4(0.f,0.f,0.f,0.f);
        ss += v[i].x*v[i].x + v[i].y*v[i].y + v[i].z*v[i].z + v[i].w*v[i].w;
    }
    partial[tid] = ss;
    __syncthreads();
    if (tid < 16) {
        float sum = 0.f;
        #pragma unroll
        for (int k = 0; k < 16; ++k) sum += partial[k * 16 + tid];
        invS[tid] = (sum > 0.f) ? rsqrtf(sum) : 0.f;
    }
    __syncthreads();
    float s = invS[rho];
    #pragma unroll
    for (int i = 0; i < 10; ++i) {
        int k = kc * 40 + i * 4;
        split_store(v[i], s, &Sh[rho][k], &Sl[rho][k]);
    }
    // fused mean-partials: add this thread's 40 normalized values into acc2
    int q0b = isB ? 0 : ((rf * 16) / 100);            // block-uniform
    int qsel = (isB || !valid) ? 0 : (r / 100 - q0b); // 0 or 1
    if (valid) {
        #pragma unroll
        for (int i = 0; i < 10; ++i) {
            int k = kc * 40 + i * 4;
            atomicAdd(&acc2[qsel][k],     v[i].x * s);
            atomicAdd(&acc2[qsel][k + 1], v[i].y * s);
            atomicAdd(&acc2[qsel][k + 2], v[i].z * s);
            atomicAdd(&acc2[qsel][k + 3], v[i].w * s);
        }
    }
    __syncthreads();

    // frag-order writes
    int lane = tid & 63, wvv = tid >> 6;
    int rs = lane & 15, kg = lane >> 4;
    char* wsb = (char*)ws;
    if (isB) {
        #pragma unroll
        for (int p = 0; p < 5; ++p) {
            int kt = wvv * 5 + p;
            short8 hv = *(const short8*)&Sh[rs][kt * 32 + kg * 8];
            short8 lv = *(const short8*)&Sl[rs][kt * 32 + kg * 8];
            size_t fo = ((size_t)(bw * 32 + rf) * 20 + kt) * 1024 + lane * 16;
            *(short8*)(wsb + WS_BH_BYTE + fo) = hv;
            *(short8*)(wsb + WS_BL_BYTE + fo) = lv;
        }
        // flush proto partial (sum over this block's rows)
        for (int c = tid; c < 640; c += 256)
            atomicAdd(&ws[WS_PROTO + bw * D + c], acc2[0][c]);
    } else {
        #pragma unroll
        for (int p = 0; p < 5; ++p) {
            int kt = wvv * 5 + p;
            short8 hv = *(const short8*)&Sh[rs][kt * 32 + kg * 8];
            short8 lv = *(const short8*)&Sl[rs][kt * 32 + kg * 8];
            size_t fo = ((size_t)(b * NRF + rf) * 20 + kt) * 1024 + lane * 16;
            *(short8*)(wsb + WS_AH_BYTE + fo) = hv;
            *(short8*)(wsb + WS_AL_BYTE + fo) = lv;
        }
        // flush qmean partials (1 or 2 q slots)
        if (q0b < Q) {
            int rl = rf * 16 + 15; if (rl > QROWS - 1) rl = QROWS - 1;
            int qlast = rl / 100;
            for (int c = tid; c < 640; c += 256) {
                atomicAdd(&ws[WS_QMEAN + (b * Q + q0b) * D + c], acc2[0][c]);
                if (qlast > q0b)
                    atomicAdd(&ws[WS_QMEAN + (b * Q + qlast) * D + c], acc2[1][c]);
            }
        }
    }
}

// ---------------- kernel 3: cosine-prototype logits + zero-init sim slots ------
// qm/pr now hold SUMS; logits = dot(qsum, psum) / (HW*M).
__global__ void cos_kernel(float* __restrict__ ws) {
    int idx  = (int)((blockIdx.x * blockDim.x + threadIdx.x) >> 6);
    int lane = threadIdx.x & 63;
    if (idx >= BB * Q * WAY) return;
    int w = idx % WAY; int bq = idx / WAY; int b = bq / Q;
    const float* qm = ws + WS_QMEAN + bq * D;
    const float* pr = ws + WS_PROTO + (b * WAY + w) * D;
    float s = 0.f;
    #pragma unroll
    for (int j = 0; j < D; j += 64) s += qm[j + lane] * pr[j + lane];
    for (int off = 32; off; off >>= 1) s += __shfl_down(s, off);
    if (lane == 0) {
        ws[WS_FEAT + bq * 10 + w]     = s * (1.0f / (HW * (float)M));
        ws[WS_FEAT + bq * 10 + 5 + w] = 0.f;
    }
}

// ---------------- kernel 4: LDS-staged GEMM + PARALLEL top-5 (R4, proven) ------
#define NRT 59
#define NBLK 1180

#define LDS_BYTES 147456
#define AB_L 8192u        // A-lo frags at 8192 + fr*1024 (A-hi at fr*1024)
#define BBASE 16384u      // B dbuf: half h at BBASE + h*65536; lo at +32768
#define BHALF 65536u
#define B_LO 32768u
#define MS_OFF 131584u    // partial top-5 buffer: 512*5*4 = 10240 B

#define AS3 __attribute__((address_space(3)))
#define AS1 __attribute__((address_space(1)))

__device__ __forceinline__ void gl16(const void* g, AS3 char* l) {
    __builtin_amdgcn_global_load_lds((const AS1 unsigned int*)g,
                                     (AS3 unsigned int*)l, 16, 0, 0);
}

#define BAR()   __builtin_amdgcn_s_barrier()
#define SB0()   __builtin_amdgcn_sched_barrier(0)
#define WAITV0() asm volatile("s_waitcnt vmcnt(0)")
#define LGKM(n)  asm volatile("s_waitcnt lgkmcnt(" #n ")")

// branchless sorted insert of v into descending (a0..a4)
#define INS5(a0,a1,a2,a3,a4,v) { \
    float n0 = fminf(a0, v); a0 = fmaxf(a0, v); \
    float n1 = fminf(a1, n0); a1 = fmaxf(a1, n0); \
    float n2 = fminf(a2, n1); a2 = fmaxf(a2, n1); \
    float n3 = fminf(a3, n2); a3 = fmaxf(a3, n2); \
    a4 = fmaxf(a4, n3); }

__global__ __launch_bounds__(512, 2) void dn4_kernel(const float* __restrict__ ws_ro,
                                                     float* __restrict__ ws) {
    __shared__ __attribute__((aligned(16))) char lds[LDS_BYTES];
    AS3 char* lp = (AS3 char*)lds;

    // bijective XCD swizzle for 1180 = 4*148 + 4*147
    int bid = blockIdx.x;
    int xcd = bid & 7, li = bid >> 3;
    int wg = (xcd < 4) ? (xcd * 148 + li) : (592 + (xcd - 4) * 147 + li);
    int bw = wg / NRT;     // 0..19 (contiguous per XCD -> B stays L2-hot)
    int rt = wg % NRT;     // 0..58
    int wy = bw % WAY, b = bw / WAY;

    int tid  = threadIdx.x;
    int lane = tid & 63;
    int wv   = tid >> 6;          // wave 0..7
    int wr   = wv >> 2;           // 0..1  (row half: 64 rows)
    int wc   = wv & 3;            // 0..3  (col strip: 128 cols)
    int lq   = lane >> 4, lfree = lane & 15;

    const char* gbase = (const char*)ws_ro;

    // ---- stage source/dest setup (per wave; all LDS dests wave-uniform) ----
    int frA = rt * 8 + wv;                           // <= 58*8+7 = 471 < NRF
    unsigned aOff  = (unsigned)((b * NRF + frA) * 20) * 1024u + (unsigned)(lane * 16);
    unsigned aDstH = (unsigned)(wv * 1024);
    unsigned aDstL = AB_L + (unsigned)(wv * 1024);
    unsigned bOff[4];
    unsigned bDst[4];
    #pragma unroll
    for (int g = 0; g < 4; ++g) {
        unsigned c = (unsigned)((wv >> 1) * 8 + 2 * g + (wv & 1));   // fragcol 0..31
        bDst[g] = BBASE + c * 1024u;
        bOff[g] = (unsigned)((bw * 32 + (int)c) * 20) * 1024u + (unsigned)(lane * 16);
    }

    #define ISS_A(t2) { \
        gl16(gbase + (size_t)(WS_AH_BYTE + aOff + (unsigned)(t2) * 1024u), lp + aDstH); \
        gl16(gbase + (size_t)(WS_AL_BYTE + aOff + (unsigned)(t2) * 1024u), lp + aDstL); }
    #define ISS_B(g, t2, hwr) { \
        unsigned dd = bDst[g] + (unsigned)(hwr) * BHALF; \
        gl16(gbase + (size_t)(WS_BH_BYTE + bOff[g] + (unsigned)(t2) * 1024u), lp + dd); \
        gl16(gbase + (size_t)(WS_BL_BYTE + bOff[g] + (unsigned)(t2) * 1024u), lp + dd + B_LO); }

    // prologue: stage tile 0 (half 0 + A slot), 10 gl16 in flight
    ISS_A(0); ISS_B(0, 0, 0); ISS_B(1, 0, 0); ISS_B(2, 0, 0); ISS_B(3, 0, 0);

    float4v acc[4][8];
    #pragma unroll
    for (int jj = 0; jj < 4; ++jj)
        #pragma unroll
        for (int ii = 0; ii < 8; ++ii) {
            acc[jj][ii][0]=0.f; acc[jj][ii][1]=0.f; acc[jj][ii][2]=0.f; acc[jj][ii][3]=0.f;
        }

    unsigned aRd[4];
    #pragma unroll
    for (int jj = 0; jj < 4; ++jj)
        aRd[jj] = (unsigned)((wr * 4 + jj) * 1024 + lane * 16);
    unsigned bRdBase = (unsigned)(wc * 8 * 1024 + lane * 16);

    short8 ah[4], al[4];
    short8 bh0, bl0, bh1, bl1;    // two B register banks (1 col each: hi+lo)

    #define RD_A() { \
        _Pragma("unroll") \
        for (int jj = 0; jj < 4; ++jj) { \
            ah[jj] = *(const AS3 short8*)(lp + aRd[jj]); \
            al[jj] = *(const AS3 short8*)(lp + aRd[jj] + AB_L); \
        } }
    #define RD2(BH, BL, ADDR) { \
        BH = *(const AS3 short8*)(lp + (ADDR)); \
        BL = *(const AS3 short8*)(lp + (ADDR) + B_LO); }

    // 12 MFMAs on one B column; per-acc order HH,HL,LH (bit-identical)
    #define MFMA_COL(ii, BH, BL) { \
        __builtin_amdgcn_s_setprio(1); \
        _Pragma("unroll") \
        for (int jj = 0; jj < 4; ++jj) \
            acc[jj][ii] = __builtin_amdgcn_mfma_f32_16x16x32_bf16(ah[jj], BH, acc[jj][ii], 0,0,0); \
        _Pragma("unroll") \
        for (int jj = 0; jj < 4; ++jj) \
            acc[jj][ii] = __builtin_amdgcn_mfma_f32_16x16x32_bf16(ah[jj], BL, acc[jj][ii], 0,0,0); \
        _Pragma("unroll") \
        for (int jj = 0; jj < 4; ++jj) \
            acc[jj][ii] = __builtin_amdgcn_mfma_f32_16x16x32_bf16(al[jj], BH, acc[jj][ii], 0,0,0); \
        __builtin_amdgcn_s_setprio(0); }

    #pragma unroll 1
    for (int kt = 0; kt < 20; ++kt) {
        int hr = kt & 1;
        unsigned bbB = BBASE + (unsigned)hr * BHALF + bRdBase;

        // validate kt's buffers: in-flight == exactly kt's 10 loads
        WAITV0();
        BAR(); SB0();

        // read burst: A first (8 reads), then first two B cols (4 reads)
        RD_A(); SB0();
        RD2(bh0, bl0, bbB);
        RD2(bh1, bl1, bbB + 1024u);
        SB0();
        LGKM(4); SB0();          // all A reads complete (last 4 = B c0,c1)

        if (kt < 19) {
            BAR(); SB0();        // all waves' A reads done -> safe to restage
            int t2 = kt + 1, hw2 = hr ^ 1;
            ISS_B(0, t2, hw2); ISS_B(1, t2, hw2); ISS_A(t2);
            ISS_B(2, t2, hw2); ISS_B(3, t2, hw2);
            SB0();
        }

        // 8 column sub-phases; prefetch col ii+2 behind col ii's MFMAs
        MFMA_COL(0, bh0, bl0);  RD2(bh0, bl0, bbB + 2u * 1024u);
        MFMA_COL(1, bh1, bl1);  RD2(bh1, bl1, bbB + 3u * 1024u);
        MFMA_COL(2, bh0, bl0);  RD2(bh0, bl0, bbB + 4u * 1024u);
        MFMA_COL(3, bh1, bl1);  RD2(bh1, bl1, bbB + 5u * 1024u);
        MFMA_COL(4, bh0, bl0);  RD2(bh0, bl0, bbB + 6u * 1024u);
        MFMA_COL(5, bh1, bl1);  RD2(bh1, bl1, bbB + 7u * 1024u);
        MFMA_COL(6, bh0, bl0);
        MFMA_COL(7, bh1, bl1);
    }

    // ---- epilogue: PARALLEL top-5 --------------------------------------------
    AS3 float* Csf = (AS3 float*)lp;                 // [128][257]
    AS3 float* Ms  = (AS3 float*)(lp + MS_OFF);      // [512][5]
    float t0=-1e30f,t1=-1e30f,t2=-1e30f,t3=-1e30f,t4=-1e30f;
    int srow = tid & 127;
    int cq   = tid >> 7;

    #pragma unroll 1
    for (int pass = 0; pass < 2; ++pass) {
        __syncthreads();
        if ((wc >> 1) == pass) {
            #pragma unroll
            for (int jj = 0; jj < 4; ++jj)
                #pragma unroll
                for (int ii = 0; ii < 8; ++ii) {
                    int row = wr * 64 + jj * 16 + lq * 4;
                    int col = (wc & 1) * 128 + ii * 16 + lfree;
                    #pragma unroll
                    for (int rr = 0; rr < 4; ++rr)
                        Csf[(row + rr) * 257 + col] = acc[jj][ii][rr];
                }
        }
        __syncthreads();
        int validc = pass ? (M - 256) : 256;   // pass1: cols 256..499 -> 244
        int vlim = validc - (cq << 6);         // per-thread valid count in chunk
        const AS3 float* rowp = Csf + srow * 257 + (cq << 6);
        #pragma unroll 8
        for (int c = 0; c < 64; ++c) {
            float v = rowp[c];
            v = (c < vlim) ? v : -1e30f;
            INS5(t0, t1, t2, t3, t4, v);
        }
    }

    __syncthreads();
    {
        AS3 float* mp = Ms + tid * 5;
        mp[0] = t0; mp[1] = t1; mp[2] = t2; mp[3] = t3; mp[4] = t4;
    }
    __syncthreads();
    if (tid < 128) {
        float u0=-1e30f,u1=-1e30f,u2=-1e30f,u3=-1e30f,u4=-1e30f;
        #pragma unroll
        for (int k = 0; k < 4; ++k) {
            const AS3 float* qp = Ms + (tid + (k << 7)) * 5;
            #pragma unroll
            for (int j = 0; j < 5; ++j) {
                float v = qp[j];
                INS5(u0, u1, u2, u3, u4, v);
            }
        }
        int rowg = rt * 128 + tid;
        if (rowg < QROWS) {
            int q = rowg / HW;
            atomicAdd(&ws[WS_FEAT + (b * Q + q) * 10 + 5 + wy],
                      (u0 + u1 + u2 + u3 + u4) * (1.f / M));
        }
    }
}

// ---------------- kernel 5: BatchNorm (training stats over q) + dilated conv ---
__global__ void bn_conv_kernel(const float* __restrict__ gamma, const float* __restrict__ beta,
                               const float* __restrict__ convw, const float* __restrict__ wsr,
                               float* __restrict__ out) {
    __shared__ float mu[10], rstd[10];
    int b = blockIdx.x;
    const float* feat = wsr + WS_FEAT + b * Q * 10;
    int t = threadIdx.x;
    if (t < 10) {
        float s = 0.f;
        for (int q = 0; q < Q; ++q) s += feat[q * 10 + t];
        float m = s / Q;
        float ss = 0.f;
        for (int q = 0; q < Q; ++q) { float d = feat[q * 10 + t] - m; ss += d * d; }
        mu[t] = m;
        rstd[t] = rsqrtf(ss / Q + 1e-5f);
    }
    __syncthreads();
    if (t < Q * WAY) {
        int q = t / WAY, j = t % WAY;
        float bn0 = (feat[q * 10 + j]     - mu[j])     * rstd[j]     * gamma[j]     + beta[j];
        float bn1 = (feat[q * 10 + 5 + j] - mu[5 + j]) * rstd[5 + j] * gamma[5 + j] + beta[5 + j];
        out[(b * Q + q) * WAY + j] = convw[0] * bn0 + convw[1] * bn1;
    }
}

extern "C" void kernel_launch(void* const* d_in, const int* in_sizes, int n_in,
                              void* d_out, int out_size, void* d_ws, size_t ws_size,
                              hipStream_t stream) {
    const float* xq    = (const float*)d_in[0];
    const float* xs    = (const float*)d_in[1];
    const float* gamma = (const float*)d_in[2];
    const float* beta  = (const float*)d_in[3];
    const float* convw = (const float*)d_in[4];
    float* ws  = (float*)d_ws;
    float* out = (float*)d_out;

    zero_kernel<<<256, 256, 0, stream>>>(ws);               // zero qmean/proto sums
    presplit_ab<<<640 + BB * NRF, 256, 0, stream>>>(xq, xs, ws);
    cos_kernel<<<(BB * Q * WAY + 3) / 4, 256, 0, stream>>>(ws);
    dn4_kernel<<<NBLK, 512, 0, stream>>>(ws, ws);
    bn_conv_kernel<<<BB, 384, 0, stream>>>(gamma, beta, convw, ws, out);
}

// Round 8
// 476.663 us; speedup vs baseline: 1.2279x; 1.2279x over previous
//
#include <hip/hip_runtime.h>

// Problem constants (fixed by setup_inputs)
#define BB 4
#define Q 75
#define WAY 5
#define HW 100
#define D 640
#define M 500          // shot*HW
#define QROWS 7500     // Q*HW
#define NRF 472        // padded row-frags per b: 59 blocks * 8 (7552 rows)

// ws layout: floats at low offsets, pre-split frag-order arrays after.
#define WS_FEAT 244800    // BB*Q*10 = 3000 floats (cos slots 0..4, sim slots 5..9)
#define WS_BH_BYTE 1048576u                       // 20*32*20*1024 = 13107200
#define WS_BL_BYTE (1048576u + 13107200u)         // 14155776
#define WS_AH_BYTE (14155776u + 13107200u)        // 27262976; 4*472*20*1024 = 38666240
#define WS_AL_BYTE (27262976u + 38666240u)        // 65929216; end 104595456

using short8  = __attribute__((ext_vector_type(8))) short;
using short4v = __attribute__((ext_vector_type(4))) short;
using float4v = __attribute__((ext_vector_type(4))) float;

__device__ __forceinline__ void split1(float v, unsigned short& h, unsigned short& l) {
    unsigned u = __float_as_uint(v);
    unsigned short hu = (unsigned short)(u >> 16);          // truncate to bf16
    float hf = __uint_as_float(u & 0xffff0000u);
    float lo = v - hf;                                       // exact residual
    unsigned short lu = (unsigned short)(__float_as_uint(lo) >> 16);
    h = hu; l = lu;
}

__device__ __forceinline__ void split_store(float4 v, float s, short* dh, short* dl) {
    unsigned short h0,h1,h2,h3,l0,l1,l2,l3;
    split1(v.x * s, h0, l0); split1(v.y * s, h1, l1);
    split1(v.z * s, h2, l2); split1(v.w * s, h3, l3);
    short4v hv, lv;
    hv[0]=(short)h0; hv[1]=(short)h1; hv[2]=(short)h2; hv[3]=(short)h3;
    lv[0]=(short)l0; lv[1]=(short)l1; lv[2]=(short)l2; lv[3]=(short)l3;
    *(short4v*)dh = hv;
    *(short4v*)dl = lv;
}

// ---------------- kernel 0a: pre-split B (normalize + bf16 hi/lo, frag-order) --
// Block 0 also zeroes the WS_FEAT accumulators (re-poison safe, runs per launch).
__global__ __launch_bounds__(256) void presplit_b(const float* __restrict__ xs,
                                                  float* __restrict__ ws) {
    __shared__ float partial[256];
    __shared__ float sinvS[16];
    __shared__ short Sh[16][648];
    __shared__ short Sl[16][648];
    int bw = blockIdx.x >> 5;      // 0..19
    int rf = blockIdx.x & 31;      // 0..31
    int tid = threadIdx.x;
    if (blockIdx.x == 0) {
        for (int i = tid; i < BB * Q * 10; i += 256) ws[WS_FEAT + i] = 0.f;
    }
    int rho = tid & 15;
    int kc  = tid >> 4;            // 0..15, k in [kc*40, kc*40+40)
    int m = rf * 16 + rho;
    bool valid = (m < M);
    const float* src = xs + ((size_t)bw * M + (valid ? m : 0)) * D + kc * 40;

    float4 v[10];
    float ss = 0.f;
    #pragma unroll
    for (int i = 0; i < 10; ++i) {
        v[i] = valid ? *(const float4*)(src + i * 4) : make_float4(0.f,0.f,0.f,0.f);
        ss += v[i].x*v[i].x + v[i].y*v[i].y + v[i].z*v[i].z + v[i].w*v[i].w;
    }
    partial[tid] = ss;
    __syncthreads();
    if (tid < 16) {
        float sum = 0.f;
        #pragma unroll
        for (int k = 0; k < 16; ++k) sum += partial[k * 16 + tid];
        sinvS[tid] = (sum > 0.f) ? rsqrtf(sum) : 0.f;
    }
    __syncthreads();
    float s = sinvS[rho];
    #pragma unroll
    for (int i = 0; i < 10; ++i) {
        int k = kc * 40 + i * 4;
        split_store(v[i], s, &Sh[rho][k], &Sl[rho][k]);
    }
    __syncthreads();
    int lane = tid & 63, wvv = tid >> 6;
    int rs = lane & 15, kg = lane >> 4;
    char* wsb = (char*)ws;
    #pragma unroll
    for (int p = 0; p < 5; ++p) {
        int kt = wvv * 5 + p;
        short8 hv = *(const short8*)&Sh[rs][kt * 32 + kg * 8];
        short8 lv = *(const short8*)&Sl[rs][kt * 32 + kg * 8];
        size_t fo = ((size_t)(bw * 32 + rf) * 20 + kt) * 1024 + lane * 16;
        *(short8*)(wsb + WS_BH_BYTE + fo) = hv;
        *(short8*)(wsb + WS_BL_BYTE + fo) = lv;
    }
}

// ---------------- kernel 0b: pre-split A (normalize + bf16 hi/lo, frag-order) --
__global__ __launch_bounds__(256) void presplit_a(const float* __restrict__ xq,
                                                  float* __restrict__ ws) {
    __shared__ float partial[256];
    __shared__ float qinvS[16];
    __shared__ short Sh[16][648];
    __shared__ short Sl[16][648];
    int b  = blockIdx.x / NRF;
    int rf = blockIdx.x % NRF;     // 0..471
    int tid = threadIdx.x;
    int rho = tid & 15;
    int kc  = tid >> 4;
    int r = rf * 16 + rho;
    bool valid = (r < QROWS);
    const float* src = xq + ((size_t)b * QROWS + (valid ? r : 0)) * D + kc * 40;

    float4 v[10];
    float ss = 0.f;
    #pragma unroll
    for (int i = 0; i < 10; ++i) {
        v[i] = valid ? *(const float4*)(src + i * 4) : make_float4(0.f,0.f,0.f,0.f);
        ss += v[i].x*v[i].x + v[i].y*v[i].y + v[i].z*v[i].z + v[i].w*v[i].w;
    }
    partial[tid] = ss;
    __syncthreads();
    if (tid < 16) {
        float sum = 0.f;
        #pragma unroll
        for (int k = 0; k < 16; ++k) sum += partial[k * 16 + tid];
        qinvS[tid] = (sum > 0.f) ? rsqrtf(sum) : 0.f;
    }
    __syncthreads();
    float s = qinvS[rho];
    #pragma unroll
    for (int i = 0; i < 10; ++i) {
        int k = kc * 40 + i * 4;
        split_store(v[i], s, &Sh[rho][k], &Sl[rho][k]);
    }
    __syncthreads();
    int lane = tid & 63, wvv = tid >> 6;
    int rs = lane & 15, kg = lane >> 4;
    char* wsb = (char*)ws;
    #pragma unroll
    for (int p = 0; p < 5; ++p) {
        int kt = wvv * 5 + p;
        short8 hv = *(const short8*)&Sh[rs][kt * 32 + kg * 8];
        short8 lv = *(const short8*)&Sl[rs][kt * 32 + kg * 8];
        size_t fo = ((size_t)(b * NRF + rf) * 20 + kt) * 1024 + lane * 16;
        *(short8*)(wsb + WS_AH_BYTE + fo) = hv;
        *(short8*)(wsb + WS_AL_BYTE + fo) = lv;
    }
}

// ---------------- kernel 4: LDS-staged GEMM + top-5 + FUSED cosine branch ------
// K-loop identical to R4 (proven 311 us). Epilogue additionally accumulates the
// per-row FULL sum of the C tile: logits_cos = (1/(HW*M)) * sum_{h,m} inner —
// algebraically identical to mean_h(qn) . mean_m(sn). This replaces
// means_kernel + cos_kernel entirely.
#define NRT 59
#define NBLK 1180

#define LDS_BYTES 147456
#define AB_L 8192u        // A-lo frags at 8192 + fr*1024 (A-hi at fr*1024)
#define BBASE 16384u      // B dbuf: half h at BBASE + h*65536; lo at +32768
#define BHALF 65536u
#define B_LO 32768u
#define MS_OFF 131584u    // partial top-5 buffer: 512*5*4 = 10240 B
#define RS_OFF 141824u    // partial row-sum buffer: 512*4 = 2048 B

#define AS3 __attribute__((address_space(3)))
#define AS1 __attribute__((address_space(1)))

__device__ __forceinline__ void gl16(const void* g, AS3 char* l) {
    __builtin_amdgcn_global_load_lds((const AS1 unsigned int*)g,
                                     (AS3 unsigned int*)l, 16, 0, 0);
}

#define BAR()   __builtin_amdgcn_s_barrier()
#define SB0()   __builtin_amdgcn_sched_barrier(0)
#define WAITV0() asm volatile("s_waitcnt vmcnt(0)")
#define LGKM(n)  asm volatile("s_waitcnt lgkmcnt(" #n ")")

// branchless sorted insert of v into descending (a0..a4)
#define INS5(a0,a1,a2,a3,a4,v) { \
    float n0 = fminf(a0, v); a0 = fmaxf(a0, v); \
    float n1 = fminf(a1, n0); a1 = fmaxf(a1, n0); \
    float n2 = fminf(a2, n1); a2 = fmaxf(a2, n1); \
    float n3 = fminf(a3, n2); a3 = fmaxf(a3, n2); \
    a4 = fmaxf(a4, n3); }

__global__ __launch_bounds__(512, 2) void dn4_kernel(const float* __restrict__ ws_ro,
                                                     float* __restrict__ ws) {
    __shared__ __attribute__((aligned(16))) char lds[LDS_BYTES];
    AS3 char* lp = (AS3 char*)lds;

    // bijective XCD swizzle for 1180 = 4*148 + 4*147
    int bid = blockIdx.x;
    int xcd = bid & 7, li = bid >> 3;
    int wg = (xcd < 4) ? (xcd * 148 + li) : (592 + (xcd - 4) * 147 + li);
    int bw = wg / NRT;     // 0..19 (contiguous per XCD -> B stays L2-hot)
    int rt = wg % NRT;     // 0..58
    int wy = bw % WAY, b = bw / WAY;

    int tid  = threadIdx.x;
    int lane = tid & 63;
    int wv   = tid >> 6;          // wave 0..7
    int wr   = wv >> 2;           // 0..1  (row half: 64 rows)
    int wc   = wv & 3;            // 0..3  (col strip: 128 cols)
    int lq   = lane >> 4, lfree = lane & 15;

    const char* gbase = (const char*)ws_ro;

    // ---- stage source/dest setup (per wave; all LDS dests wave-uniform) ----
    int frA = rt * 8 + wv;                           // <= 58*8+7 = 471 < NRF
    unsigned aOff  = (unsigned)((b * NRF + frA) * 20) * 1024u + (unsigned)(lane * 16);
    unsigned aDstH = (unsigned)(wv * 1024);
    unsigned aDstL = AB_L + (unsigned)(wv * 1024);
    unsigned bOff[4];
    unsigned bDst[4];
    #pragma unroll
    for (int g = 0; g < 4; ++g) {
        unsigned c = (unsigned)((wv >> 1) * 8 + 2 * g + (wv & 1));   // fragcol 0..31
        bDst[g] = BBASE + c * 1024u;
        bOff[g] = (unsigned)((bw * 32 + (int)c) * 20) * 1024u + (unsigned)(lane * 16);
    }

    #define ISS_A(t2) { \
        gl16(gbase + (size_t)(WS_AH_BYTE + aOff + (unsigned)(t2) * 1024u), lp + aDstH); \
        gl16(gbase + (size_t)(WS_AL_BYTE + aOff + (unsigned)(t2) * 1024u), lp + aDstL); }
    #define ISS_B(g, t2, hwr) { \
        unsigned dd = bDst[g] + (unsigned)(hwr) * BHALF; \
        gl16(gbase + (size_t)(WS_BH_BYTE + bOff[g] + (unsigned)(t2) * 1024u), lp + dd); \
        gl16(gbase + (size_t)(WS_BL_BYTE + bOff[g] + (unsigned)(t2) * 1024u), lp + dd + B_LO); }

    // prologue: stage tile 0 (half 0 + A slot), 10 gl16 in flight
    ISS_A(0); ISS_B(0, 0, 0); ISS_B(1, 0, 0); ISS_B(2, 0, 0); ISS_B(3, 0, 0);

    float4v acc[4][8];
    #pragma unroll
    for (int jj = 0; jj < 4; ++jj)
        #pragma unroll
        for (int ii = 0; ii < 8; ++ii) {
            acc[jj][ii][0]=0.f; acc[jj][ii][1]=0.f; acc[jj][ii][2]=0.f; acc[jj][ii][3]=0.f;
        }

    unsigned aRd[4];
    #pragma unroll
    for (int jj = 0; jj < 4; ++jj)
        aRd[jj] = (unsigned)((wr * 4 + jj) * 1024 + lane * 16);
    unsigned bRdBase = (unsigned)(wc * 8 * 1024 + lane * 16);

    short8 ah[4], al[4];
    short8 bh0, bl0, bh1, bl1;    // two B register banks (1 col each: hi+lo)

    #define RD_A() { \
        _Pragma("unroll") \
        for (int jj = 0; jj < 4; ++jj) { \
            ah[jj] = *(const AS3 short8*)(lp + aRd[jj]); \
            al[jj] = *(const AS3 short8*)(lp + aRd[jj] + AB_L); \
        } }
    #define RD2(BH, BL, ADDR) { \
        BH = *(const AS3 short8*)(lp + (ADDR)); \
        BL = *(const AS3 short8*)(lp + (ADDR) + B_LO); }

    // 12 MFMAs on one B column; per-acc order HH,HL,LH (bit-identical)
    #define MFMA_COL(ii, BH, BL) { \
        __builtin_amdgcn_s_setprio(1); \
        _Pragma("unroll") \
        for (int jj = 0; jj < 4; ++jj) \
            acc[jj][ii] = __builtin_amdgcn_mfma_f32_16x16x32_bf16(ah[jj], BH, acc[jj][ii], 0,0,0); \
        _Pragma("unroll") \
        for (int jj = 0; jj < 4; ++jj) \
            acc[jj][ii] = __builtin_amdgcn_mfma_f32_16x16x32_bf16(ah[jj], BL, acc[jj][ii], 0,0,0); \
        _Pragma("unroll") \
        for (int jj = 0; jj < 4; ++jj) \
            acc[jj][ii] = __builtin_amdgcn_mfma_f32_16x16x32_bf16(al[jj], BH, acc[jj][ii], 0,0,0); \
        __builtin_amdgcn_s_setprio(0); }

    #pragma unroll 1
    for (int kt = 0; kt < 20; ++kt) {
        int hr = kt & 1;
        unsigned bbB = BBASE + (unsigned)hr * BHALF + bRdBase;

        // validate kt's buffers: in-flight == exactly kt's 10 loads
        WAITV0();
        BAR(); SB0();

        // read burst: A first (8 reads), then first two B cols (4 reads)
        RD_A(); SB0();
        RD2(bh0, bl0, bbB);
        RD2(bh1, bl1, bbB + 1024u);
        SB0();
        LGKM(4); SB0();          // all A reads complete (last 4 = B c0,c1)

        if (kt < 19) {
            BAR(); SB0();        // all waves' A reads done -> safe to restage
            int t2 = kt + 1, hw2 = hr ^ 1;
            ISS_B(0, t2, hw2); ISS_B(1, t2, hw2); ISS_A(t2);
            ISS_B(2, t2, hw2); ISS_B(3, t2, hw2);
            SB0();
        }

        // 8 column sub-phases; prefetch col ii+2 behind col ii's MFMAs
        MFMA_COL(0, bh0, bl0);  RD2(bh0, bl0, bbB + 2u * 1024u);
        MFMA_COL(1, bh1, bl1);  RD2(bh1, bl1, bbB + 3u * 1024u);
        MFMA_COL(2, bh0, bl0);  RD2(bh0, bl0, bbB + 4u * 1024u);
        MFMA_COL(3, bh1, bl1);  RD2(bh1, bl1, bbB + 5u * 1024u);
        MFMA_COL(4, bh0, bl0);  RD2(bh0, bl0, bbB + 6u * 1024u);
        MFMA_COL(5, bh1, bl1);  RD2(bh1, bl1, bbB + 7u * 1024u);
        MFMA_COL(6, bh0, bl0);
        MFMA_COL(7, bh1, bl1);
    }

    // ---- epilogue: PARALLEL top-5 + per-row full sum (fused cosine) ----------
    AS3 float* Csf = (AS3 float*)lp;                 // [128][257]
    AS3 float* Ms  = (AS3 float*)(lp + MS_OFF);      // [512][5]
    AS3 float* Rs  = (AS3 float*)(lp + RS_OFF);      // [512]
    float t0=-1e30f,t1=-1e30f,t2=-1e30f,t3=-1e30f,t4=-1e30f;
    float rsum = 0.f;
    int srow = tid & 127;
    int cq   = tid >> 7;

    #pragma unroll 1
    for (int pass = 0; pass < 2; ++pass) {
        __syncthreads();
        if ((wc >> 1) == pass) {
            #pragma unroll
            for (int jj = 0; jj < 4; ++jj)
                #pragma unroll
                for (int ii = 0; ii < 8; ++ii) {
                    int row = wr * 64 + jj * 16 + lq * 4;
                    int col = (wc & 1) * 128 + ii * 16 + lfree;
                    #pragma unroll
                    for (int rr = 0; rr < 4; ++rr)
                        Csf[(row + rr) * 257 + col] = acc[jj][ii][rr];
                }
        }
        __syncthreads();
        int validc = pass ? (M - 256) : 256;   // pass1: cols 256..499 -> 244
        int vlim = validc - (cq << 6);         // per-thread valid count in chunk
        const AS3 float* rowp = Csf + srow * 257 + (cq << 6);
        #pragma unroll 8
        for (int c = 0; c < 64; ++c) {
            float vraw = rowp[c];
            bool ok = (c < vlim);
            rsum += ok ? vraw : 0.f;
            float v = ok ? vraw : -1e30f;
            INS5(t0, t1, t2, t3, t4, v);
        }
    }

    __syncthreads();
    {
        AS3 float* mp = Ms + tid * 5;
        mp[0] = t0; mp[1] = t1; mp[2] = t2; mp[3] = t3; mp[4] = t4;
        Rs[tid] = rsum;
    }
    __syncthreads();
    if (tid < 128) {
        float u0=-1e30f,u1=-1e30f,u2=-1e30f,u3=-1e30f,u4=-1e30f;
        #pragma unroll
        for (int k = 0; k < 4; ++k) {
            const AS3 float* qp = Ms + (tid + (k << 7)) * 5;
            #pragma unroll
            for (int j = 0; j < 5; ++j) {
                float v = qp[j];
                INS5(u0, u1, u2, u3, u4, v);
            }
        }
        float rowsum = Rs[tid] + Rs[tid + 128] + Rs[tid + 256] + Rs[tid + 384];
        int rowg = rt * 128 + tid;
        if (rowg < QROWS) {
            int q = rowg / HW;
            atomicAdd(&ws[WS_FEAT + (b * Q + q) * 10 + 5 + wy],
                      (u0 + u1 + u2 + u3 + u4) * (1.f / M));
            atomicAdd(&ws[WS_FEAT + (b * Q + q) * 10 + wy],
                      rowsum * (1.f / (HW * (float)M)));
        }
    }
}

// ---------------- kernel 5: BatchNorm (training stats over q) + dilated conv ---
__global__ void bn_conv_kernel(const float* __restrict__ gamma, const float* __restrict__ beta,
                               const float* __restrict__ convw, const float* __restrict__ wsr,
                               float* __restrict__ out) {
    __shared__ float mu[10], rstd[10];
    int b = blockIdx.x;
    const float* feat = wsr + WS_FEAT + b * Q * 10;
    int t = threadIdx.x;
    if (t < 10) {
        float s = 0.f;
        for (int q = 0; q < Q; ++q) s += feat[q * 10 + t];
        float m = s / Q;
        float ss = 0.f;
        for (int q = 0; q < Q; ++q) { float d = feat[q * 10 + t] - m; ss += d * d; }
        mu[t] = m;
        rstd[t] = rsqrtf(ss / Q + 1e-5f);
    }
    __syncthreads();
    if (t < Q * WAY) {
        int q = t / WAY, j = t % WAY;
        float bn0 = (feat[q * 10 + j]     - mu[j])     * rstd[j]     * gamma[j]     + beta[j];
        float bn1 = (feat[q * 10 + 5 + j] - mu[5 + j]) * rstd[5 + j] * gamma[5 + j] + beta[5 + j];
        out[(b * Q + q) * WAY + j] = convw[0] * bn0 + convw[1] * bn1;
    }
}

extern "C" void kernel_launch(void* const* d_in, const int* in_sizes, int n_in,
                              void* d_out, int out_size, void* d_ws, size_t ws_size,
                              hipStream_t stream) {
    const float* xq    = (const float*)d_in[0];
    const float* xs    = (const float*)d_in[1];
    const float* gamma = (const float*)d_in[2];
    const float* beta  = (const float*)d_in[3];
    const float* convw = (const float*)d_in[4];
    float* ws  = (float*)d_ws;
    float* out = (float*)d_out;

    presplit_b<<<20 * 32, 256, 0, stream>>>(xs, ws);       // frag-order B + feat zero
    presplit_a<<<BB * NRF, 256, 0, stream>>>(xq, ws);      // frag-order A
    dn4_kernel<<<NBLK, 512, 0, stream>>>(ws, ws);
    bn_conv_kernel<<<BB, 384, 0, stream>>>(gamma, beta, convw, ws, out);
}

// Round 9
// 453.375 us; speedup vs baseline: 1.2910x; 1.0514x over previous
//
#include <hip/hip_runtime.h>

// Problem constants (fixed by setup_inputs)
#define BB 4
#define Q 75
#define WAY 5
#define HW 100
#define D 640
#define M 500          // shot*HW
#define QROWS 7500     // Q*HW
#define NRF 472        // padded row-frags per b: 59 blocks * 8 (7552 rows)

// ws layout: floats at low offsets, pre-split frag-order arrays after.
#define WS_FEAT 244800    // BB*Q*10 = 3000 floats (cos slots 0..4, sim slots 5..9)
#define WS_BH_BYTE 1048576u                       // 20*32*20*1024 = 13107200
#define WS_BL_BYTE (1048576u + 13107200u)         // 14155776
#define WS_AH_BYTE (14155776u + 13107200u)        // 27262976; 4*472*20*1024 = 38666240
#define WS_AL_BYTE (27262976u + 38666240u)        // 65929216; end 104595456

using short8  = __attribute__((ext_vector_type(8))) short;
using short4v = __attribute__((ext_vector_type(4))) short;
using float4v = __attribute__((ext_vector_type(4))) float;

__device__ __forceinline__ void split1(float v, unsigned short& h, unsigned short& l) {
    unsigned u = __float_as_uint(v);
    unsigned short hu = (unsigned short)(u >> 16);          // truncate to bf16
    float hf = __uint_as_float(u & 0xffff0000u);
    float lo = v - hf;                                       // exact residual
    unsigned short lu = (unsigned short)(__float_as_uint(lo) >> 16);
    h = hu; l = lu;
}

__device__ __forceinline__ void split_store(float4 v, float s, short* dh, short* dl) {
    unsigned short h0,h1,h2,h3,l0,l1,l2,l3;
    split1(v.x * s, h0, l0); split1(v.y * s, h1, l1);
    split1(v.z * s, h2, l2); split1(v.w * s, h3, l3);
    short4v hv, lv;
    hv[0]=(short)h0; hv[1]=(short)h1; hv[2]=(short)h2; hv[3]=(short)h3;
    lv[0]=(short)l0; lv[1]=(short)l1; lv[2]=(short)l2; lv[3]=(short)l3;
    *(short4v*)dh = hv;
    *(short4v*)dl = lv;
}

// ---------------- kernel 0: MERGED pre-split A+B, coalesced via LDS round-trip -
// bid < 640: B-mode (bw = bid>>5, rf = bid&31); else A-mode over (b, rf).
// Phase 1: 10 x 4KB fully-coalesced chunk loads into LDS stage (row pad +16B).
// Phase 2: thread (rho,kc) reads its 40 floats from stage -> ss -> reduce.
// Phase 3: split to bf16 hi/lo in Sh/Sl (overlays stage) -> frag-order stores.
// All arithmetic order identical to the previous presplit kernels ->
// bit-identical ws contents. Block 0 zeroes the WS_FEAT accumulators.
__global__ __launch_bounds__(256) void presplit_ab(const float* __restrict__ xq,
                                                   const float* __restrict__ xs,
                                                   float* __restrict__ ws) {
    __shared__ __attribute__((aligned(16))) char smem[42560];
    float* partial = (float*)smem;                       // 256 f
    float* invS    = (float*)(smem + 1024);              // 16 f
    char*  stage   = smem + 1088;                        // 16 rows x 2576 B
    short (*Sh)[648] = (short (*)[648])(smem + 1088);    // overlays stage
    short (*Sl)[648] = (short (*)[648])(smem + 1088 + 20736);

    int bid = blockIdx.x;
    int tid = threadIdx.x;
    if (bid == 0) {
        for (int i = tid; i < BB * Q * 10; i += 256) ws[WS_FEAT + i] = 0.f;
    }

    bool isB = (bid < 640);
    int bw = 0, b = 0, rf, rowbase, limit;
    const char* srcbase;
    if (isB) {
        bw = bid >> 5; rf = bid & 31;
        rowbase = rf * 16; limit = M;
        srcbase = (const char*)(xs + ((size_t)bw * M + rowbase) * D);
    } else {
        int a = bid - 640;
        b = a / NRF; rf = a % NRF;
        rowbase = rf * 16; limit = QROWS;
        srcbase = (const char*)(xq + ((size_t)b * QROWS + rowbase) * D);
    }

    // phase 1: coalesced stage (predicated against tail-block OOB -> zeros)
    #pragma unroll
    for (int i = 0; i < 10; ++i) {
        int off = i * 4096 + tid * 16;          // byte offset within 40KB block
        int rl  = off / 2560;                   // local row 0..15 (const-div)
        bool ok = (rowbase + rl < limit);
        float4 vv = ok ? *(const float4*)(srcbase + off)
                       : make_float4(0.f, 0.f, 0.f, 0.f);
        *(float4*)(stage + off + rl * 16) = vv; // +16B pad per row
    }
    __syncthreads();

    // phase 2: per-(rho,kc) slice from LDS; ss in the original order
    int rho = tid & 15;
    int kc  = tid >> 4;
    float4 v[10];
    float ss = 0.f;
    #pragma unroll
    for (int i = 0; i < 10; ++i) {
        v[i] = *(const float4*)(stage + rho * 2576 + kc * 160 + i * 16);
        ss += v[i].x*v[i].x + v[i].y*v[i].y + v[i].z*v[i].z + v[i].w*v[i].w;
    }
    partial[tid] = ss;
    __syncthreads();
    if (tid < 16) {
        float sum = 0.f;
        #pragma unroll
        for (int k = 0; k < 16; ++k) sum += partial[k * 16 + tid];
        invS[tid] = (sum > 0.f) ? rsqrtf(sum) : 0.f;
    }
    __syncthreads();

    // phase 3: split into Sh/Sl (overlays stage; all stage reads done)
    float s = invS[rho];
    #pragma unroll
    for (int i = 0; i < 10; ++i) {
        int k = kc * 40 + i * 4;
        split_store(v[i], s, &Sh[rho][k], &Sl[rho][k]);
    }
    __syncthreads();

    int lane = tid & 63, wvv = tid >> 6;
    int rs = lane & 15, kg = lane >> 4;
    char* wsb = (char*)ws;
    if (isB) {
        #pragma unroll
        for (int p = 0; p < 5; ++p) {
            int kt = wvv * 5 + p;
            short8 hv = *(const short8*)&Sh[rs][kt * 32 + kg * 8];
            short8 lv = *(const short8*)&Sl[rs][kt * 32 + kg * 8];
            size_t fo = ((size_t)(bw * 32 + rf) * 20 + kt) * 1024 + lane * 16;
            *(short8*)(wsb + WS_BH_BYTE + fo) = hv;
            *(short8*)(wsb + WS_BL_BYTE + fo) = lv;
        }
    } else {
        #pragma unroll
        for (int p = 0; p < 5; ++p) {
            int kt = wvv * 5 + p;
            short8 hv = *(const short8*)&Sh[rs][kt * 32 + kg * 8];
            short8 lv = *(const short8*)&Sl[rs][kt * 32 + kg * 8];
            size_t fo = ((size_t)(b * NRF + rf) * 20 + kt) * 1024 + lane * 16;
            *(short8*)(wsb + WS_AH_BYTE + fo) = hv;
            *(short8*)(wsb + WS_AL_BYTE + fo) = lv;
        }
    }
}

// ---------------- kernel 4: LDS-staged GEMM + top-5 + FUSED cosine branch ------
// Byte-identical to round 8 (control; proven passing).
#define NRT 59
#define NBLK 1180

#define LDS_BYTES 147456
#define AB_L 8192u        // A-lo frags at 8192 + fr*1024 (A-hi at fr*1024)
#define BBASE 16384u      // B dbuf: half h at BBASE + h*65536; lo at +32768
#define BHALF 65536u
#define B_LO 32768u
#define MS_OFF 131584u    // partial top-5 buffer: 512*5*4 = 10240 B
#define RS_OFF 141824u    // partial row-sum buffer: 512*4 = 2048 B

#define AS3 __attribute__((address_space(3)))
#define AS1 __attribute__((address_space(1)))

__device__ __forceinline__ void gl16(const void* g, AS3 char* l) {
    __builtin_amdgcn_global_load_lds((const AS1 unsigned int*)g,
                                     (AS3 unsigned int*)l, 16, 0, 0);
}

#define BAR()   __builtin_amdgcn_s_barrier()
#define SB0()   __builtin_amdgcn_sched_barrier(0)
#define WAITV0() asm volatile("s_waitcnt vmcnt(0)")
#define LGKM(n)  asm volatile("s_waitcnt lgkmcnt(" #n ")")

// branchless sorted insert of v into descending (a0..a4)
#define INS5(a0,a1,a2,a3,a4,v) { \
    float n0 = fminf(a0, v); a0 = fmaxf(a0, v); \
    float n1 = fminf(a1, n0); a1 = fmaxf(a1, n0); \
    float n2 = fminf(a2, n1); a2 = fmaxf(a2, n1); \
    float n3 = fminf(a3, n2); a3 = fmaxf(a3, n2); \
    a4 = fmaxf(a4, n3); }

__global__ __launch_bounds__(512, 2) void dn4_kernel(const float* __restrict__ ws_ro,
                                                     float* __restrict__ ws) {
    __shared__ __attribute__((aligned(16))) char lds[LDS_BYTES];
    AS3 char* lp = (AS3 char*)lds;

    // bijective XCD swizzle for 1180 = 4*148 + 4*147
    int bid = blockIdx.x;
    int xcd = bid & 7, li = bid >> 3;
    int wg = (xcd < 4) ? (xcd * 148 + li) : (592 + (xcd - 4) * 147 + li);
    int bw = wg / NRT;     // 0..19 (contiguous per XCD -> B stays L2-hot)
    int rt = wg % NRT;     // 0..58
    int wy = bw % WAY, b = bw / WAY;

    int tid  = threadIdx.x;
    int lane = tid & 63;
    int wv   = tid >> 6;          // wave 0..7
    int wr   = wv >> 2;           // 0..1  (row half: 64 rows)
    int wc   = wv & 3;            // 0..3  (col strip: 128 cols)
    int lq   = lane >> 4, lfree = lane & 15;

    const char* gbase = (const char*)ws_ro;

    // ---- stage source/dest setup (per wave; all LDS dests wave-uniform) ----
    int frA = rt * 8 + wv;                           // <= 58*8+7 = 471 < NRF
    unsigned aOff  = (unsigned)((b * NRF + frA) * 20) * 1024u + (unsigned)(lane * 16);
    unsigned aDstH = (unsigned)(wv * 1024);
    unsigned aDstL = AB_L + (unsigned)(wv * 1024);
    unsigned bOff[4];
    unsigned bDst[4];
    #pragma unroll
    for (int g = 0; g < 4; ++g) {
        unsigned c = (unsigned)((wv >> 1) * 8 + 2 * g + (wv & 1));   // fragcol 0..31
        bDst[g] = BBASE + c * 1024u;
        bOff[g] = (unsigned)((bw * 32 + (int)c) * 20) * 1024u + (unsigned)(lane * 16);
    }

    #define ISS_A(t2) { \
        gl16(gbase + (size_t)(WS_AH_BYTE + aOff + (unsigned)(t2) * 1024u), lp + aDstH); \
        gl16(gbase + (size_t)(WS_AL_BYTE + aOff + (unsigned)(t2) * 1024u), lp + aDstL); }
    #define ISS_B(g, t2, hwr) { \
        unsigned dd = bDst[g] + (unsigned)(hwr) * BHALF; \
        gl16(gbase + (size_t)(WS_BH_BYTE + bOff[g] + (unsigned)(t2) * 1024u), lp + dd); \
        gl16(gbase + (size_t)(WS_BL_BYTE + bOff[g] + (unsigned)(t2) * 1024u), lp + dd + B_LO); }

    // prologue: stage tile 0 (half 0 + A slot), 10 gl16 in flight
    ISS_A(0); ISS_B(0, 0, 0); ISS_B(1, 0, 0); ISS_B(2, 0, 0); ISS_B(3, 0, 0);

    float4v acc[4][8];
    #pragma unroll
    for (int jj = 0; jj < 4; ++jj)
        #pragma unroll
        for (int ii = 0; ii < 8; ++ii) {
            acc[jj][ii][0]=0.f; acc[jj][ii][1]=0.f; acc[jj][ii][2]=0.f; acc[jj][ii][3]=0.f;
        }

    unsigned aRd[4];
    #pragma unroll
    for (int jj = 0; jj < 4; ++jj)
        aRd[jj] = (unsigned)((wr * 4 + jj) * 1024 + lane * 16);
    unsigned bRdBase = (unsigned)(wc * 8 * 1024 + lane * 16);

    short8 ah[4], al[4];
    short8 bh0, bl0, bh1, bl1;    // two B register banks (1 col each: hi+lo)

    #define RD_A() { \
        _Pragma("unroll") \
        for (int jj = 0; jj < 4; ++jj) { \
            ah[jj] = *(const AS3 short8*)(lp + aRd[jj]); \
            al[jj] = *(const AS3 short8*)(lp + aRd[jj] + AB_L); \
        } }
    #define RD2(BH, BL, ADDR) { \
        BH = *(const AS3 short8*)(lp + (ADDR)); \
        BL = *(const AS3 short8*)(lp + (ADDR) + B_LO); }

    // 12 MFMAs on one B column; per-acc order HH,HL,LH (bit-identical)
    #define MFMA_COL(ii, BH, BL) { \
        __builtin_amdgcn_s_setprio(1); \
        _Pragma("unroll") \
        for (int jj = 0; jj < 4; ++jj) \
            acc[jj][ii] = __builtin_amdgcn_mfma_f32_16x16x32_bf16(ah[jj], BH, acc[jj][ii], 0,0,0); \
        _Pragma("unroll") \
        for (int jj = 0; jj < 4; ++jj) \
            acc[jj][ii] = __builtin_amdgcn_mfma_f32_16x16x32_bf16(ah[jj], BL, acc[jj][ii], 0,0,0); \
        _Pragma("unroll") \
        for (int jj = 0; jj < 4; ++jj) \
            acc[jj][ii] = __builtin_amdgcn_mfma_f32_16x16x32_bf16(al[jj], BH, acc[jj][ii], 0,0,0); \
        __builtin_amdgcn_s_setprio(0); }

    #pragma unroll 1
    for (int kt = 0; kt < 20; ++kt) {
        int hr = kt & 1;
        unsigned bbB = BBASE + (unsigned)hr * BHALF + bRdBase;

        // validate kt's buffers: in-flight == exactly kt's 10 loads
        WAITV0();
        BAR(); SB0();

        // read burst: A first (8 reads), then first two B cols (4 reads)
        RD_A(); SB0();
        RD2(bh0, bl0, bbB);
        RD2(bh1, bl1, bbB + 1024u);
        SB0();
        LGKM(4); SB0();          // all A reads complete (last 4 = B c0,c1)

        if (kt < 19) {
            BAR(); SB0();        // all waves' A reads done -> safe to restage
            int t2 = kt + 1, hw2 = hr ^ 1;
            ISS_B(0, t2, hw2); ISS_B(1, t2, hw2); ISS_A(t2);
            ISS_B(2, t2, hw2); ISS_B(3, t2, hw2);
            SB0();
        }

        // 8 column sub-phases; prefetch col ii+2 behind col ii's MFMAs
        MFMA_COL(0, bh0, bl0);  RD2(bh0, bl0, bbB + 2u * 1024u);
        MFMA_COL(1, bh1, bl1);  RD2(bh1, bl1, bbB + 3u * 1024u);
        MFMA_COL(2, bh0, bl0);  RD2(bh0, bl0, bbB + 4u * 1024u);
        MFMA_COL(3, bh1, bl1);  RD2(bh1, bl1, bbB + 5u * 1024u);
        MFMA_COL(4, bh0, bl0);  RD2(bh0, bl0, bbB + 6u * 1024u);
        MFMA_COL(5, bh1, bl1);  RD2(bh1, bl1, bbB + 7u * 1024u);
        MFMA_COL(6, bh0, bl0);
        MFMA_COL(7, bh1, bl1);
    }

    // ---- epilogue: PARALLEL top-5 + per-row full sum (fused cosine) ----------
    AS3 float* Csf = (AS3 float*)lp;                 // [128][257]
    AS3 float* Ms  = (AS3 float*)(lp + MS_OFF);      // [512][5]
    AS3 float* Rs  = (AS3 float*)(lp + RS_OFF);      // [512]
    float t0=-1e30f,t1=-1e30f,t2=-1e30f,t3=-1e30f,t4=-1e30f;
    float rsum = 0.f;
    int srow = tid & 127;
    int cq   = tid >> 7;

    #pragma unroll 1
    for (int pass = 0; pass < 2; ++pass) {
        __syncthreads();
        if ((wc >> 1) == pass) {
            #pragma unroll
            for (int jj = 0; jj < 4; ++jj)
                #pragma unroll
                for (int ii = 0; ii < 8; ++ii) {
                    int row = wr * 64 + jj * 16 + lq * 4;
                    int col = (wc & 1) * 128 + ii * 16 + lfree;
                    #pragma unroll
                    for (int rr = 0; rr < 4; ++rr)
                        Csf[(row + rr) * 257 + col] = acc[jj][ii][rr];
                }
        }
        __syncthreads();
        int validc = pass ? (M - 256) : 256;   // pass1: cols 256..499 -> 244
        int vlim = validc - (cq << 6);         // per-thread valid count in chunk
        const AS3 float* rowp = Csf + srow * 257 + (cq << 6);
        #pragma unroll 8
        for (int c = 0; c < 64; ++c) {
            float vraw = rowp[c];
            bool ok = (c < vlim);
            rsum += ok ? vraw : 0.f;
            float v = ok ? vraw : -1e30f;
            INS5(t0, t1, t2, t3, t4, v);
        }
    }

    __syncthreads();
    {
        AS3 float* mp = Ms + tid * 5;
        mp[0] = t0; mp[1] = t1; mp[2] = t2; mp[3] = t3; mp[4] = t4;
        Rs[tid] = rsum;
    }
    __syncthreads();
    if (tid < 128) {
        float u0=-1e30f,u1=-1e30f,u2=-1e30f,u3=-1e30f,u4=-1e30f;
        #pragma unroll
        for (int k = 0; k < 4; ++k) {
            const AS3 float* qp = Ms + (tid + (k << 7)) * 5;
            #pragma unroll
            for (int j = 0; j < 5; ++j) {
                float v = qp[j];
                INS5(u0, u1, u2, u3, u4, v);
            }
        }
        float rowsum = Rs[tid] + Rs[tid + 128] + Rs[tid + 256] + Rs[tid + 384];
        int rowg = rt * 128 + tid;
        if (rowg < QROWS) {
            int q = rowg / HW;
            atomicAdd(&ws[WS_FEAT + (b * Q + q) * 10 + 5 + wy],
                      (u0 + u1 + u2 + u3 + u4) * (1.f / M));
            atomicAdd(&ws[WS_FEAT + (b * Q + q) * 10 + wy],
                      rowsum * (1.f / (HW * (float)M)));
        }
    }
}

// ---------------- kernel 5: BatchNorm (training stats over q) + dilated conv ---
// feat staged to LDS once (coalesced, parallel) instead of 150 serial global
// loads per stat thread. Same summation order -> bit-identical output.
__global__ void bn_conv_kernel(const float* __restrict__ gamma, const float* __restrict__ beta,
                               const float* __restrict__ convw, const float* __restrict__ wsr,
                               float* __restrict__ out) {
    __shared__ float f[Q * 10];
    __shared__ float mu[10], rstd[10];
    int b = blockIdx.x;
    const float* feat = wsr + WS_FEAT + b * Q * 10;
    int t = threadIdx.x;
    for (int i = t; i < Q * 10; i += 384) f[i] = feat[i];
    __syncthreads();
    if (t < 10) {
        float s = 0.f;
        for (int q = 0; q < Q; ++q) s += f[q * 10 + t];
        float m = s / Q;
        float ss = 0.f;
        for (int q = 0; q < Q; ++q) { float d = f[q * 10 + t] - m; ss += d * d; }
        mu[t] = m;
        rstd[t] = rsqrtf(ss / Q + 1e-5f);
    }
    __syncthreads();
    if (t < Q * WAY) {
        int q = t / WAY, j = t % WAY;
        float bn0 = (f[q * 10 + j]     - mu[j])     * rstd[j]     * gamma[j]     + beta[j];
        float bn1 = (f[q * 10 + 5 + j] - mu[5 + j]) * rstd[5 + j] * gamma[5 + j] + beta[5 + j];
        out[(b * Q + q) * WAY + j] = convw[0] * bn0 + convw[1] * bn1;
    }
}

extern "C" void kernel_launch(void* const* d_in, const int* in_sizes, int n_in,
                              void* d_out, int out_size, void* d_ws, size_t ws_size,
                              hipStream_t stream) {
    const float* xq    = (const float*)d_in[0];
    const float* xs    = (const float*)d_in[1];
    const float* gamma = (const float*)d_in[2];
    const float* beta  = (const float*)d_in[3];
    const float* convw = (const float*)d_in[4];
    float* ws  = (float*)d_ws;
    float* out = (float*)d_out;

    presplit_ab<<<640 + BB * NRF, 256, 0, stream>>>(xq, xs, ws);
    dn4_kernel<<<NBLK, 512, 0, stream>>>(ws, ws);
    bn_conv_kernel<<<BB, 384, 0, stream>>>(gamma, beta, convw, ws, out);
}

// Round 10
// 393.725 us; speedup vs baseline: 1.4865x; 1.1515x over previous
//
#include <hip/hip_runtime.h>

// Problem constants (fixed by setup_inputs)
#define BB 4
#define Q 75
#define WAY 5
#define HW 100
#define D 640
#define M 500          // shot*HW
#define QROWS 7500     // Q*HW
#define NRF 472        // padded row-frags per b: 59 blocks * 8 (7552 rows)

// ws layout: floats at low offsets, pre-split frag-order arrays after.
#define WS_FEAT 244800    // BB*Q*10 = 3000 floats (cos slots 0..4, sim slots 5..9)
#define WS_BH_BYTE 1048576u                       // 20*32*20*1024 = 13107200
#define WS_BL_BYTE (1048576u + 13107200u)         // 14155776
#define WS_AH_BYTE (14155776u + 13107200u)        // 27262976; 4*472*20*1024 = 38666240
#define WS_AL_BYTE (27262976u + 38666240u)        // unused since r10 (LH term dropped)

using short8  = __attribute__((ext_vector_type(8))) short;
using short4v = __attribute__((ext_vector_type(4))) short;
using float4v = __attribute__((ext_vector_type(4))) float;

__device__ __forceinline__ void split1(float v, unsigned short& h, unsigned short& l) {
    unsigned u = __float_as_uint(v);
    unsigned short hu = (unsigned short)(u >> 16);          // truncate to bf16
    float hf = __uint_as_float(u & 0xffff0000u);
    float lo = v - hf;                                       // exact residual
    unsigned short lu = (unsigned short)(__float_as_uint(lo) >> 16);
    h = hu; l = lu;
}

__device__ __forceinline__ void split_store(float4 v, float s, short* dh, short* dl) {
    unsigned short h0,h1,h2,h3,l0,l1,l2,l3;
    split1(v.x * s, h0, l0); split1(v.y * s, h1, l1);
    split1(v.z * s, h2, l2); split1(v.w * s, h3, l3);
    short4v hv, lv;
    hv[0]=(short)h0; hv[1]=(short)h1; hv[2]=(short)h2; hv[3]=(short)h3;
    lv[0]=(short)l0; lv[1]=(short)l1; lv[2]=(short)l2; lv[3]=(short)l3;
    *(short4v*)dh = hv;
    *(short4v*)dl = lv;
}

// hi-only variant (A-side since r10: LH correction term dropped)
__device__ __forceinline__ void trunc_store4(float4 v, float s, short* dh) {
    short4v hv;
    hv[0] = (short)(unsigned short)(__float_as_uint(v.x * s) >> 16);
    hv[1] = (short)(unsigned short)(__float_as_uint(v.y * s) >> 16);
    hv[2] = (short)(unsigned short)(__float_as_uint(v.z * s) >> 16);
    hv[3] = (short)(unsigned short)(__float_as_uint(v.w * s) >> 16);
    *(short4v*)dh = hv;
}

// ---------------- kernel 0: MERGED pre-split A+B, coalesced via LDS round-trip -
// bid < 640: B-mode (hi+lo); else A-mode (hi ONLY — 38.7 MB of writes removed).
// Phase 1: 10 x 4KB fully-coalesced chunk loads into LDS stage (row pad +16B).
// Phase 2: thread (rho,kc) reads its 40 floats from stage -> ss -> reduce.
// Phase 3: split to bf16 in Sh(/Sl) -> frag-order stores.
// Block 0 zeroes the WS_FEAT accumulators (re-poison safe).
__global__ __launch_bounds__(256) void presplit_ab(const float* __restrict__ xq,
                                                   const float* __restrict__ xs,
                                                   float* __restrict__ ws) {
    __shared__ __attribute__((aligned(16))) char smem[42560];
    float* partial = (float*)smem;                       // 256 f
    float* invS    = (float*)(smem + 1024);              // 16 f
    char*  stage   = smem + 1088;                        // 16 rows x 2576 B
    short (*Sh)[648] = (short (*)[648])(smem + 1088);    // overlays stage
    short (*Sl)[648] = (short (*)[648])(smem + 1088 + 20736);

    int bid = blockIdx.x;
    int tid = threadIdx.x;
    if (bid == 0) {
        for (int i = tid; i < BB * Q * 10; i += 256) ws[WS_FEAT + i] = 0.f;
    }

    bool isB = (bid < 640);
    int bw = 0, b = 0, rf, rowbase, limit;
    const char* srcbase;
    if (isB) {
        bw = bid >> 5; rf = bid & 31;
        rowbase = rf * 16; limit = M;
        srcbase = (const char*)(xs + ((size_t)bw * M + rowbase) * D);
    } else {
        int a = bid - 640;
        b = a / NRF; rf = a % NRF;
        rowbase = rf * 16; limit = QROWS;
        srcbase = (const char*)(xq + ((size_t)b * QROWS + rowbase) * D);
    }

    // phase 1: coalesced stage (predicated against tail-block OOB -> zeros)
    #pragma unroll
    for (int i = 0; i < 10; ++i) {
        int off = i * 4096 + tid * 16;          // byte offset within 40KB block
        int rl  = off / 2560;                   // local row 0..15 (const-div)
        bool ok = (rowbase + rl < limit);
        float4 vv = ok ? *(const float4*)(srcbase + off)
                       : make_float4(0.f, 0.f, 0.f, 0.f);
        *(float4*)(stage + off + rl * 16) = vv; // +16B pad per row
    }
    __syncthreads();

    // phase 2: per-(rho,kc) slice from LDS; ss in the original order
    int rho = tid & 15;
    int kc  = tid >> 4;
    float4 v[10];
    float ss = 0.f;
    #pragma unroll
    for (int i = 0; i < 10; ++i) {
        v[i] = *(const float4*)(stage + rho * 2576 + kc * 160 + i * 16);
        ss += v[i].x*v[i].x + v[i].y*v[i].y + v[i].z*v[i].z + v[i].w*v[i].w;
    }
    partial[tid] = ss;
    __syncthreads();
    if (tid < 16) {
        float sum = 0.f;
        #pragma unroll
        for (int k = 0; k < 16; ++k) sum += partial[k * 16 + tid];
        invS[tid] = (sum > 0.f) ? rsqrtf(sum) : 0.f;
    }
    __syncthreads();

    // phase 3: split into Sh(/Sl) (overlays stage; all stage reads done)
    float s = invS[rho];
    if (isB) {
        #pragma unroll
        for (int i = 0; i < 10; ++i) {
            int k = kc * 40 + i * 4;
            split_store(v[i], s, &Sh[rho][k], &Sl[rho][k]);
        }
    } else {
        #pragma unroll
        for (int i = 0; i < 10; ++i) {
            int k = kc * 40 + i * 4;
            trunc_store4(v[i], s, &Sh[rho][k]);
        }
    }
    __syncthreads();

    int lane = tid & 63, wvv = tid >> 6;
    int rs = lane & 15, kg = lane >> 4;
    char* wsb = (char*)ws;
    if (isB) {
        #pragma unroll
        for (int p = 0; p < 5; ++p) {
            int kt = wvv * 5 + p;
            short8 hv = *(const short8*)&Sh[rs][kt * 32 + kg * 8];
            short8 lv = *(const short8*)&Sl[rs][kt * 32 + kg * 8];
            size_t fo = ((size_t)(bw * 32 + rf) * 20 + kt) * 1024 + lane * 16;
            *(short8*)(wsb + WS_BH_BYTE + fo) = hv;
            *(short8*)(wsb + WS_BL_BYTE + fo) = lv;
        }
    } else {
        #pragma unroll
        for (int p = 0; p < 5; ++p) {
            int kt = wvv * 5 + p;
            short8 hv = *(const short8*)&Sh[rs][kt * 32 + kg * 8];
            size_t fo = ((size_t)(b * NRF + rf) * 20 + kt) * 1024 + lane * 16;
            *(short8*)(wsb + WS_AH_BYTE + fo) = hv;
        }
    }
}

// ---------------- kernel 4: LDS-staged GEMM + top-5 + FUSED cosine branch ------
// R4 sync structure (proven). Since r10: LH (a_lo*b_hi) MFMA term dropped ->
// 64 MFMAs/kt/wave (HH+HL), A staged hi-only (9 gl16/kt), 20 ds_reads/kt.
#define NRT 59
#define NBLK 1180

#define LDS_BYTES 147456
#define BBASE 16384u      // B dbuf: half h at BBASE + h*65536; lo at +32768
#define BHALF 65536u
#define B_LO 32768u
#define MS_OFF 131584u    // partial top-5 buffer: 512*5*4 = 10240 B
#define RS_OFF 141824u    // partial row-sum buffer: 512*4 = 2048 B

#define AS3 __attribute__((address_space(3)))
#define AS1 __attribute__((address_space(1)))

__device__ __forceinline__ void gl16(const void* g, AS3 char* l) {
    __builtin_amdgcn_global_load_lds((const AS1 unsigned int*)g,
                                     (AS3 unsigned int*)l, 16, 0, 0);
}

#define BAR()   __builtin_amdgcn_s_barrier()
#define SB0()   __builtin_amdgcn_sched_barrier(0)
#define WAITV0() asm volatile("s_waitcnt vmcnt(0)")
#define LGKM(n)  asm volatile("s_waitcnt lgkmcnt(" #n ")")

// branchless sorted insert of v into descending (a0..a4)
#define INS5(a0,a1,a2,a3,a4,v) { \
    float n0 = fminf(a0, v); a0 = fmaxf(a0, v); \
    float n1 = fminf(a1, n0); a1 = fmaxf(a1, n0); \
    float n2 = fminf(a2, n1); a2 = fmaxf(a2, n1); \
    float n3 = fminf(a3, n2); a3 = fmaxf(a3, n2); \
    a4 = fmaxf(a4, n3); }

__global__ __launch_bounds__(512, 2) void dn4_kernel(const float* __restrict__ ws_ro,
                                                     float* __restrict__ ws) {
    __shared__ __attribute__((aligned(16))) char lds[LDS_BYTES];
    AS3 char* lp = (AS3 char*)lds;

    // bijective XCD swizzle for 1180 = 4*148 + 4*147
    int bid = blockIdx.x;
    int xcd = bid & 7, li = bid >> 3;
    int wg = (xcd < 4) ? (xcd * 148 + li) : (592 + (xcd - 4) * 147 + li);
    int bw = wg / NRT;     // 0..19 (contiguous per XCD -> B stays L2-hot)
    int rt = wg % NRT;     // 0..58
    int wy = bw % WAY, b = bw / WAY;

    int tid  = threadIdx.x;
    int lane = tid & 63;
    int wv   = tid >> 6;          // wave 0..7
    int wr   = wv >> 2;           // 0..1  (row half: 64 rows)
    int wc   = wv & 3;            // 0..3  (col strip: 128 cols)
    int lq   = lane >> 4, lfree = lane & 15;

    const char* gbase = (const char*)ws_ro;

    // ---- stage source/dest setup (per wave; all LDS dests wave-uniform) ----
    int frA = rt * 8 + wv;                           // <= 58*8+7 = 471 < NRF
    unsigned aOff  = (unsigned)((b * NRF + frA) * 20) * 1024u + (unsigned)(lane * 16);
    unsigned aDstH = (unsigned)(wv * 1024);
    unsigned bOff[4];
    unsigned bDst[4];
    #pragma unroll
    for (int g = 0; g < 4; ++g) {
        unsigned c = (unsigned)((wv >> 1) * 8 + 2 * g + (wv & 1));   // fragcol 0..31
        bDst[g] = BBASE + c * 1024u;
        bOff[g] = (unsigned)((bw * 32 + (int)c) * 20) * 1024u + (unsigned)(lane * 16);
    }

    #define ISS_A(t2) { \
        gl16(gbase + (size_t)(WS_AH_BYTE + aOff + (unsigned)(t2) * 1024u), lp + aDstH); }
    #define ISS_B(g, t2, hwr) { \
        unsigned dd = bDst[g] + (unsigned)(hwr) * BHALF; \
        gl16(gbase + (size_t)(WS_BH_BYTE + bOff[g] + (unsigned)(t2) * 1024u), lp + dd); \
        gl16(gbase + (size_t)(WS_BL_BYTE + bOff[g] + (unsigned)(t2) * 1024u), lp + dd + B_LO); }

    // prologue: stage tile 0 (A hi + B half 0), 9 gl16 in flight
    ISS_A(0); ISS_B(0, 0, 0); ISS_B(1, 0, 0); ISS_B(2, 0, 0); ISS_B(3, 0, 0);

    float4v acc[4][8];
    #pragma unroll
    for (int jj = 0; jj < 4; ++jj)
        #pragma unroll
        for (int ii = 0; ii < 8; ++ii) {
            acc[jj][ii][0]=0.f; acc[jj][ii][1]=0.f; acc[jj][ii][2]=0.f; acc[jj][ii][3]=0.f;
        }

    unsigned aRd[4];
    #pragma unroll
    for (int jj = 0; jj < 4; ++jj)
        aRd[jj] = (unsigned)((wr * 4 + jj) * 1024 + lane * 16);
    unsigned bRdBase = (unsigned)(wc * 8 * 1024 + lane * 16);

    short8 ah[4];
    short8 bh0, bl0, bh1, bl1;    // two B register banks (1 col each: hi+lo)

    #define RD_A() { \
        _Pragma("unroll") \
        for (int jj = 0; jj < 4; ++jj) \
            ah[jj] = *(const AS3 short8*)(lp + aRd[jj]); }
    #define RD2(BH, BL, ADDR) { \
        BH = *(const AS3 short8*)(lp + (ADDR)); \
        BL = *(const AS3 short8*)(lp + (ADDR) + B_LO); }

    // 8 MFMAs on one B column; per-acc order HH then HL
    #define MFMA_COL(ii, BH, BL) { \
        __builtin_amdgcn_s_setprio(1); \
        _Pragma("unroll") \
        for (int jj = 0; jj < 4; ++jj) \
            acc[jj][ii] = __builtin_amdgcn_mfma_f32_16x16x32_bf16(ah[jj], BH, acc[jj][ii], 0,0,0); \
        _Pragma("unroll") \
        for (int jj = 0; jj < 4; ++jj) \
            acc[jj][ii] = __builtin_amdgcn_mfma_f32_16x16x32_bf16(ah[jj], BL, acc[jj][ii], 0,0,0); \
        __builtin_amdgcn_s_setprio(0); }

    #pragma unroll 1
    for (int kt = 0; kt < 20; ++kt) {
        int hr = kt & 1;
        unsigned bbB = BBASE + (unsigned)hr * BHALF + bRdBase;

        // validate kt's buffers: in-flight == exactly kt's 9 loads
        WAITV0();
        BAR(); SB0();

        // read burst: A first (4 reads), then first two B cols (4 reads)
        RD_A(); SB0();
        RD2(bh0, bl0, bbB);
        RD2(bh1, bl1, bbB + 1024u);
        SB0();
        LGKM(4); SB0();          // all A reads complete (last 4 = B c0,c1)

        if (kt < 19) {
            BAR(); SB0();        // all waves' A reads done -> safe to restage
            int t2 = kt + 1, hw2 = hr ^ 1;
            ISS_B(0, t2, hw2); ISS_B(1, t2, hw2); ISS_A(t2);
            ISS_B(2, t2, hw2); ISS_B(3, t2, hw2);
            SB0();
        }

        // 8 column sub-phases; prefetch col ii+2 behind col ii's MFMAs
        MFMA_COL(0, bh0, bl0);  RD2(bh0, bl0, bbB + 2u * 1024u);
        MFMA_COL(1, bh1, bl1);  RD2(bh1, bl1, bbB + 3u * 1024u);
        MFMA_COL(2, bh0, bl0);  RD2(bh0, bl0, bbB + 4u * 1024u);
        MFMA_COL(3, bh1, bl1);  RD2(bh1, bl1, bbB + 5u * 1024u);
        MFMA_COL(4, bh0, bl0);  RD2(bh0, bl0, bbB + 6u * 1024u);
        MFMA_COL(5, bh1, bl1);  RD2(bh1, bl1, bbB + 7u * 1024u);
        MFMA_COL(6, bh0, bl0);
        MFMA_COL(7, bh1, bl1);
    }

    // ---- epilogue: PARALLEL top-5 + per-row full sum (fused cosine) ----------
    AS3 float* Csf = (AS3 float*)lp;                 // [128][257]
    AS3 float* Ms  = (AS3 float*)(lp + MS_OFF);      // [512][5]
    AS3 float* Rs  = (AS3 float*)(lp + RS_OFF);      // [512]
    float t0=-1e30f,t1=-1e30f,t2=-1e30f,t3=-1e30f,t4=-1e30f;
    float rsum = 0.f;
    int srow = tid & 127;
    int cq   = tid >> 7;

    #pragma unroll 1
    for (int pass = 0; pass < 2; ++pass) {
        __syncthreads();
        if ((wc >> 1) == pass) {
            #pragma unroll
            for (int jj = 0; jj < 4; ++jj)
                #pragma unroll
                for (int ii = 0; ii < 8; ++ii) {
                    int row = wr * 64 + jj * 16 + lq * 4;
                    int col = (wc & 1) * 128 + ii * 16 + lfree;
                    #pragma unroll
                    for (int rr = 0; rr < 4; ++rr)
                        Csf[(row + rr) * 257 + col] = acc[jj][ii][rr];
                }
        }
        __syncthreads();
        int validc = pass ? (M - 256) : 256;   // pass1: cols 256..499 -> 244
        int vlim = validc - (cq << 6);         // per-thread valid count in chunk
        const AS3 float* rowp = Csf + srow * 257 + (cq << 6);
        #pragma unroll 8
        for (int c = 0; c < 64; ++c) {
            float vraw = rowp[c];
            bool ok = (c < vlim);
            rsum += ok ? vraw : 0.f;
            float v = ok ? vraw : -1e30f;
            INS5(t0, t1, t2, t3, t4, v);
        }
    }

    __syncthreads();
    {
        AS3 float* mp = Ms + tid * 5;
        mp[0] = t0; mp[1] = t1; mp[2] = t2; mp[3] = t3; mp[4] = t4;
        Rs[tid] = rsum;
    }
    __syncthreads();
    if (tid < 128) {
        float u0=-1e30f,u1=-1e30f,u2=-1e30f,u3=-1e30f,u4=-1e30f;
        #pragma unroll
        for (int k = 0; k < 4; ++k) {
            const AS3 float* qp = Ms + (tid + (k << 7)) * 5;
            #pragma unroll
            for (int j = 0; j < 5; ++j) {
                float v = qp[j];
                INS5(u0, u1, u2, u3, u4, v);
            }
        }
        float rowsum = Rs[tid] + Rs[tid + 128] + Rs[tid + 256] + Rs[tid + 384];
        int rowg = rt * 128 + tid;
        if (rowg < QROWS) {
            int q = rowg / HW;
            atomicAdd(&ws[WS_FEAT + (b * Q + q) * 10 + 5 + wy],
                      (u0 + u1 + u2 + u3 + u4) * (1.f / M));
            atomicAdd(&ws[WS_FEAT + (b * Q + q) * 10 + wy],
                      rowsum * (1.f / (HW * (float)M)));
        }
    }
}

// ---------------- kernel 5: BatchNorm (training stats over q) + dilated conv ---
__global__ void bn_conv_kernel(const float* __restrict__ gamma, const float* __restrict__ beta,
                               const float* __restrict__ convw, const float* __restrict__ wsr,
                               float* __restrict__ out) {
    __shared__ float f[Q * 10];
    __shared__ float mu[10], rstd[10];
    int b = blockIdx.x;
    const float* feat = wsr + WS_FEAT + b * Q * 10;
    int t = threadIdx.x;
    for (int i = t; i < Q * 10; i += 384) f[i] = feat[i];
    __syncthreads();
    if (t < 10) {
        float s = 0.f;
        for (int q = 0; q < Q; ++q) s += f[q * 10 + t];
        float m = s / Q;
        float ss = 0.f;
        for (int q = 0; q < Q; ++q) { float d = f[q * 10 + t] - m; ss += d * d; }
        mu[t] = m;
        rstd[t] = rsqrtf(ss / Q + 1e-5f);
    }
    __syncthreads();
    if (t < Q * WAY) {
        int q = t / WAY, j = t % WAY;
        float bn0 = (f[q * 10 + j]     - mu[j])     * rstd[j]     * gamma[j]     + beta[j];
        float bn1 = (f[q * 10 + 5 + j] - mu[5 + j]) * rstd[5 + j] * gamma[5 + j] + beta[5 + j];
        out[(b * Q + q) * WAY + j] = convw[0] * bn0 + convw[1] * bn1;
    }
}

extern "C" void kernel_launch(void* const* d_in, const int* in_sizes, int n_in,
                              void* d_out, int out_size, void* d_ws, size_t ws_size,
                              hipStream_t stream) {
    const float* xq    = (const float*)d_in[0];
    const float* xs    = (const float*)d_in[1];
    const float* gamma = (const float*)d_in[2];
    const float* beta  = (const float*)d_in[3];
    const float* convw = (const float*)d_in[4];
    float* ws  = (float*)d_ws;
    float* out = (float*)d_out;

    presplit_ab<<<640 + BB * NRF, 256, 0, stream>>>(xq, xs, ws);
    dn4_kernel<<<NBLK, 512, 0, stream>>>(ws, ws);
    bn_conv_kernel<<<BB, 384, 0, stream>>>(gamma, beta, convw, ws, out);
}